// Round 10
// baseline (8794.511 us; speedup 1.0000x reference)
//
#include <hip/hip_runtime.h>
#include <math.h>

#define DEVI static __device__ __forceinline__

DEVI float gelu_f(float x) { return 0.5f * x * (1.0f + erff(x * 0.70710678118654752440f)); }

// ---------------------------------------------------------------------------
// Direct 3x3 conv for small Cin (stem L0-L2), stage-all-taps. (round-7 code)
// ---------------------------------------------------------------------------
template <int CIN, int NCO>
__global__ __launch_bounds__(256)
void conv3x3_t(const float* __restrict__ in, const float* __restrict__ w,
               const float* __restrict__ bias, float* __restrict__ out,
               int Cout, int Hin, int Win, int Hout, int Wout, int stride)
{
    __shared__ __align__(16) float wlds[CIN * 9 * NCO];
    int b = blockIdx.z;
    int co0 = blockIdx.y * NCO;
    int tid = threadIdx.x;
    int HWo = Hout * Wout;
    int s = blockIdx.x * 256 + tid;
    int sc = (s < HWo) ? s : (HWo - 1);
    int ho = sc / Wout, wo = sc % Wout;
    float acc[NCO];
#pragma unroll
    for (int j = 0; j < NCO; j++) acc[j] = bias[co0 + j];
    const float* inb = in + (size_t)b * CIN * Hin * Win;
    size_t HWi = (size_t)Hin * Win;

    const int nw = NCO * CIN * 9;
    for (int i = tid; i < nw; i += 256) {
        int j = i % NCO;
        int rest = i / NCO;          // tap*CIN + ci
        int ci = rest % CIN, tap = rest / CIN;
        wlds[i] = w[((size_t)(co0 + j) * CIN + ci) * 9 + tap];
    }
    __syncthreads();
    for (int kh = 0; kh < 3; kh++) {
        int hi = ho * stride - 1 + kh;
        bool okh = (hi >= 0 && hi < Hin);
        for (int kw = 0; kw < 3; kw++) {
            int wi = wo * stride - 1 + kw;
            if (!okh || wi < 0 || wi >= Win) continue;
            int tap = kh * 3 + kw;
            const float* ip = inb + (size_t)hi * Win + wi;
            const float* wp = wlds + (size_t)tap * CIN * NCO;
#pragma unroll 8
            for (int ci = 0; ci < CIN; ci++) {
                float xv = ip[(size_t)ci * HWi];
                const float* wq = wp + ci * NCO;
#pragma unroll
                for (int j4 = 0; j4 < NCO; j4 += 4) {
                    float4 wv = *(const float4*)(wq + j4);
                    acc[j4 + 0] += xv * wv.x; acc[j4 + 1] += xv * wv.y;
                    acc[j4 + 2] += xv * wv.z; acc[j4 + 3] += xv * wv.w;
                }
            }
        }
    }
    if (s < HWo) {
        size_t ob = ((size_t)b * Cout + co0) * HWo + s;
#pragma unroll
        for (int j = 0; j < NCO; j++) out[ob + (size_t)j * HWo] = acc[j];
    }
}

// ---------------------------------------------------------------------------
// Weight transpose for conv L3/L4: w[co][ci][tap] -> WT[tap][ci][co]
// ---------------------------------------------------------------------------
__global__ __launch_bounds__(256)
void wt_k(const float* __restrict__ w, float* __restrict__ WT,
          int Cin, int Cout, int total)
{
    int idx = blockIdx.x * 256 + threadIdx.x;
    if (idx >= total) return;
    int co = idx % Cout;
    int rest = idx / Cout;
    int ci = rest % Cin;
    int tap = rest / Cin;
    WT[idx] = w[((size_t)co * Cin + ci) * 9 + tap];
}

// ---------------------------------------------------------------------------
// GEMM-style conv for large Cin (stem L3/L4), v2 (round-9 code, unchanged)
// ---------------------------------------------------------------------------
template <int CIN>
__global__ __launch_bounds__(256)
void conv_gemm2_k(const float* __restrict__ in, const float* __restrict__ WT,
                  const float* __restrict__ bias, float* __restrict__ out,
                  int Cout, int Hin, int Win, int Hout, int Wout, int stride)
{
    __shared__ __align__(16) float As[16][36];   // [k][co32]
    __shared__ __align__(16) float Bs[16][68];   // [k][site64]
    int b = blockIdx.z;
    int n0 = blockIdx.x * 64;                    // site tile
    int m0 = blockIdx.y * 32;                    // cout tile
    int HWo = Hout * Wout;
    int tid = threadIdx.x;
    int tx = tid % 16, ty = tid / 16;            // tx: 4 sites, ty: 2 couts
    int wa_c = tid % 32, wa_k = tid / 32;        // As staging: co fastest
    int lb_n = tid % 64, lb_k = tid / 64;        // Bs staging
    int sb = n0 + lb_n;
    int sbc = (sb < HWo) ? sb : (HWo - 1);
    int ho_b = sbc / Wout, wo_b = sbc % Wout;
    bool site_ok = (sb < HWo);
    const float* inb = in + (size_t)b * CIN * Hin * Win;
    size_t HWi = (size_t)Hin * Win;

    float acc[2][4];
#pragma unroll
    for (int i = 0; i < 2; i++) {
        float bs = bias[m0 + ty * 2 + i];
#pragma unroll
        for (int j = 0; j < 4; j++) acc[i][j] = bs;
    }

    for (int tap = 0; tap < 9; tap++) {
        int kh = tap / 3, kw = tap % 3;
        int hi = ho_b * stride - 1 + kh;
        int wi = wo_b * stride - 1 + kw;
        bool valid = site_ok && (hi >= 0) && (hi < Hin) && (wi >= 0) && (wi < Win);
        const float* ip = inb + (size_t)hi * Win + wi;
        const float* wt = WT + (size_t)tap * CIN * Cout;
        for (int k0 = 0; k0 < CIN; k0 += 16) {
#pragma unroll
            for (int r = 0; r < 2; r++) {
                int kk = wa_k + r * 8;
                As[kk][wa_c] = wt[(size_t)(k0 + kk) * Cout + m0 + wa_c];
            }
#pragma unroll
            for (int r = 0; r < 4; r++) {
                int kk = lb_k + r * 4;
                Bs[kk][lb_n] = valid ? ip[(size_t)(k0 + kk) * HWi] : 0.f;
            }
            __syncthreads();
#pragma unroll
            for (int kk = 0; kk < 16; kk++) {
                float2 av = *(const float2*)&As[kk][ty * 2];
                float4 bv = *(const float4*)&Bs[kk][tx * 4];
                acc[0][0] += av.x * bv.x; acc[0][1] += av.x * bv.y;
                acc[0][2] += av.x * bv.z; acc[0][3] += av.x * bv.w;
                acc[1][0] += av.y * bv.x; acc[1][1] += av.y * bv.y;
                acc[1][2] += av.y * bv.z; acc[1][3] += av.y * bv.w;
            }
            __syncthreads();
        }
    }
#pragma unroll
    for (int i = 0; i < 2; i++) {
        int m = m0 + ty * 2 + i;
#pragma unroll
        for (int j = 0; j < 4; j++) {
            int n = n0 + tx * 4 + j;
            if (n < HWo)
                out[((size_t)b * Cout + m) * HWo + n] = acc[i][j];
        }
    }
}

// ---------------------------------------------------------------------------
// GroupNorm, DETERMINISTIC (round-7 code)
// ---------------------------------------------------------------------------
__global__ __launch_bounds__(256)
void gn_stats_k(const float* __restrict__ x, double* __restrict__ part,
                int C, int HW, int cpg, int S)
{
    int srt = blockIdx.x, g = blockIdx.y, b = blockIdx.z;
    long len = (long)cpg * HW;
    long chunk = (len + S - 1) / S;
    long lo = (long)srt * chunk;
    long hi = lo + chunk; if (hi > len) hi = len;
    const float* xp = x + ((size_t)b * C + (size_t)g * cpg) * HW;
    double s1 = 0.0, s2 = 0.0;
    for (long i = lo + threadIdx.x; i < hi; i += 256) {
        double v = (double)xp[i];
        s1 += v; s2 += v * v;
    }
    __shared__ double r1[256], r2[256];
    r1[threadIdx.x] = s1; r2[threadIdx.x] = s2;
    __syncthreads();
    for (int t = 128; t > 0; t >>= 1) {
        if (threadIdx.x < t) { r1[threadIdx.x] += r1[threadIdx.x + t]; r2[threadIdx.x] += r2[threadIdx.x + t]; }
        __syncthreads();
    }
    if (threadIdx.x == 0) {
        size_t slot = ((size_t)(b * 32 + g) * S + srt) * 2;
        part[slot] = r1[0];
        part[slot + 1] = r2[0];
    }
}

__global__ __launch_bounds__(64)
void gn_reduce_k(const double* __restrict__ part, float* __restrict__ fin,
                 int S, double cnt)
{
    int t = threadIdx.x;
    double s1 = 0.0, s2 = 0.0;
    for (int s = 0; s < S; s++) {
        size_t slot = ((size_t)t * S + s) * 2;
        s1 += part[slot];
        s2 += part[slot + 1];
    }
    double m = s1 / cnt;
    double var = s2 / cnt - m * m;
    double inv = 1.0 / sqrt(var + 1e-5);
    fin[t * 2] = (float)m;
    fin[t * 2 + 1] = (float)inv;
}

__global__ __launch_bounds__(256)
void gn_apply_k(float* __restrict__ x, const float* __restrict__ fin,
                const float* __restrict__ gma, const float* __restrict__ bta,
                int C, int HW, int cpg, int do_gelu, int total)
{
    int idx = blockIdx.x * 256 + threadIdx.x;
    if (idx >= total) return;
    int c = (idx / HW) % C;
    int b = idx / (HW * C);
    int g = c / cpg;
    float m = fin[(b * 32 + g) * 2];
    float inv = fin[(b * 32 + g) * 2 + 1];
    float v = (x[idx] - m) * inv * gma[c] + bta[c];
    if (do_gelu) v = gelu_f(v);
    x[idx] = v;
}

// ---------------------------------------------------------------------------
// Add DETR sine position embedding (round-7 code)
// ---------------------------------------------------------------------------
__global__ __launch_bounds__(256)
void posadd_k(const float* __restrict__ xin, float* __restrict__ xout)
{
    int idx = blockIdx.x * 256 + threadIdx.x;
    if (idx >= 2 * 256 * 2500) return;
    int t = idx % 2500;
    int ch = (idx / 2500) % 256;
    int yy = t / 50, xx = t % 50;
    int cc = ch & 127;
    double v = (double)((ch < 128) ? (yy + 1) : (xx + 1));
    v = v * (6.283185307179586476925287 / 50.0);
    double e = (double)(2 * (cc >> 1)) / 128.0;
    double d = pow(10000.0, e);
    double a = v / d;
    double p = (cc & 1) ? cos(a) : sin(a);
    xout[idx] = xin[idx] + (float)p;
}

// ---------------------------------------------------------------------------
// Pointwise GEMM (round-7 code, byte-exact)
// ---------------------------------------------------------------------------
__global__ __launch_bounds__(256)
void gemm_k(const float* __restrict__ A, const float* __restrict__ Bm,
            float* __restrict__ Cm,
            const float* __restrict__ bias, const float* __restrict__ gma,
            const float* __restrict__ bta, const float* __restrict__ res,
            int M, int N, int K, int do_gelu)
{
    __shared__ __align__(16) float As[16][68];
    __shared__ __align__(16) float Bs[16][68];
    int b = blockIdx.z;
    const float* Bp = Bm + (size_t)b * K * N;
    float* Cp = Cm + (size_t)b * M * N;
    const float* Rp = res ? res + (size_t)b * M * N : nullptr;
    int n0 = blockIdx.x * 64, m0 = blockIdx.y * 64;
    int tid = threadIdx.x;
    int tx = tid % 16, ty = tid / 16;
    int la_k = tid % 16, la_m = tid / 16;
    int lb_n = tid % 64, lb_k = tid / 64;
    float acc[4][4] = {};
    for (int k0 = 0; k0 < K; k0 += 16) {
#pragma unroll
        for (int r = 0; r < 4; r++) {
            int m = la_m + r * 16;
            As[la_k][m] = A[(size_t)(m0 + m) * K + k0 + la_k];
        }
#pragma unroll
        for (int r = 0; r < 4; r++) {
            int kk = lb_k + r * 4;
            int n = n0 + lb_n;
            Bs[kk][lb_n] = (n < N) ? Bp[(size_t)(k0 + kk) * N + n] : 0.f;
        }
        __syncthreads();
#pragma unroll
        for (int kk = 0; kk < 16; kk++) {
            float4 av = *(const float4*)&As[kk][ty * 4];
            float4 bv = *(const float4*)&Bs[kk][tx * 4];
            acc[0][0] += av.x * bv.x; acc[0][1] += av.x * bv.y; acc[0][2] += av.x * bv.z; acc[0][3] += av.x * bv.w;
            acc[1][0] += av.y * bv.x; acc[1][1] += av.y * bv.y; acc[1][2] += av.y * bv.z; acc[1][3] += av.y * bv.w;
            acc[2][0] += av.z * bv.x; acc[2][1] += av.z * bv.y; acc[2][2] += av.z * bv.z; acc[2][3] += av.z * bv.w;
            acc[3][0] += av.w * bv.x; acc[3][1] += av.w * bv.y; acc[3][2] += av.w * bv.z; acc[3][3] += av.w * bv.w;
        }
        __syncthreads();
    }
#pragma unroll
    for (int i2 = 0; i2 < 4; i2++) {
        int m = m0 + ty * 4 + i2;
        float bs = bias ? bias[m] : 0.f;
        float gm = gma[m], bt = bta[m];
#pragma unroll
        for (int j2 = 0; j2 < 4; j2++) {
            int n = n0 + tx * 4 + j2;
            if (n < N) {
                float v = (acc[i2][j2] + bs) * gm + bt;
                if (do_gelu) v = gelu_f(v);
                if (Rp) v += Rp[(size_t)m * N + n];
                Cp[(size_t)m * N + n] = v;
            }
        }
    }
}

// ---------------------------------------------------------------------------
// Per-token transpose + norms (round-7 code)
// ---------------------------------------------------------------------------
__global__ __launch_bounds__(256)
void tok_k(const float* __restrict__ Hf, float* __restrict__ HT,
           float* __restrict__ R, float* __restrict__ SQ)
{
    int t = blockIdx.x * 256 + threadIdx.x;
    if (t >= 5000) return;
    int b = t / 2500, tt = t % 2500;
    const float* p = Hf + (size_t)b * 256 * 2500 + tt;
    float* ht = HT + (size_t)t * 256;
    double s = 0.0;
    for (int c = 0; c < 256; c++) {
        float v = p[(size_t)c * 2500];
        ht[c] = v;
        s += (double)v * v;
    }
    float r = (float)(1.0 / sqrt(s + 1e-12));
    double s2 = 0.0;
    for (int c = 0; c < 256; c++) {
        float xn = ht[c] * r;
        s2 += (double)xn * xn;
    }
    R[t] = r;
    SQ[t] = (float)s2;
}

// ---------------------------------------------------------------------------
// Pairwise neg sq distance (round-7 code, byte-exact 64x64 tile)
// ---------------------------------------------------------------------------
__global__ __launch_bounds__(256)
void dist_k(const float* __restrict__ HT, const float* __restrict__ R,
            const float* __restrict__ SQ, float* __restrict__ NEGc,
            int r0, int rows)
{
    __shared__ __align__(16) float As[16][68];
    __shared__ __align__(16) float Bs[16][68];
    int b = blockIdx.z;
    const float* Xp = HT + (size_t)b * 2500 * 256;
    const float* Rp = R + (size_t)b * 2500;
    const float* Sp = SQ + (size_t)b * 2500;
    float* Np = NEGc + (size_t)b * rows * 2500;
    int n0 = blockIdx.x * 64, m0 = blockIdx.y * 64;  // m0 chunk-local
    int tid = threadIdx.x;
    int tx = tid % 16, ty = tid / 16;
    int lk = tid % 16, lr = tid / 16;
    float acc[4][4] = {};
    for (int k0 = 0; k0 < 256; k0 += 16) {
#pragma unroll
        for (int r = 0; r < 4; r++) {
            int m = lr + r * 16;
            int gi = r0 + m0 + m;
            As[lk][m] = (gi < 2500) ? Xp[(size_t)gi * 256 + k0 + lk] * Rp[gi] : 0.f;
            int gj = n0 + m;
            Bs[lk][m] = (gj < 2500) ? Xp[(size_t)gj * 256 + k0 + lk] * Rp[gj] : 0.f;
        }
        __syncthreads();
#pragma unroll
        for (int kk = 0; kk < 16; kk++) {
            float4 av = *(const float4*)&As[kk][ty * 4];
            float4 bv = *(const float4*)&Bs[kk][tx * 4];
            acc[0][0] += av.x * bv.x; acc[0][1] += av.x * bv.y; acc[0][2] += av.x * bv.z; acc[0][3] += av.x * bv.w;
            acc[1][0] += av.y * bv.x; acc[1][1] += av.y * bv.y; acc[1][2] += av.y * bv.z; acc[1][3] += av.y * bv.w;
            acc[2][0] += av.z * bv.x; acc[2][1] += av.z * bv.y; acc[2][2] += av.z * bv.z; acc[2][3] += av.z * bv.w;
            acc[3][0] += av.w * bv.x; acc[3][1] += av.w * bv.y; acc[3][2] += av.w * bv.z; acc[3][3] += av.w * bv.w;
        }
        __syncthreads();
    }
#pragma unroll
    for (int i2 = 0; i2 < 4; i2++) {
        int ml = m0 + ty * 4 + i2;
        int gi = r0 + ml;
        if (ml >= rows || gi >= 2500) continue;
        float si = Sp[gi];
#pragma unroll
        for (int j2 = 0; j2 < 4; j2++) {
            int j = n0 + tx * 4 + j2;
            if (j >= 2500) continue;
            Np[(size_t)ml * 2500 + j] = 2.f * acc[i2][j2] - si - Sp[j];
        }
    }
}

// ---------------------------------------------------------------------------
// top-(k*dil) per row v2: cached per-thread slice max + wave shuffle reduce.
// SELECTION LOGIC ONLY - produces identical indices to the v1 kernel:
// - per-thread scan ascending with strict > keeps lowest index on ties
// - cross-thread reduce ties break on lower index (each index owned by
//   exactly one thread, so global winner matches v1's full-scan winner)
// - owner thread invalidates vals[sel] and rescans only its own slice
// ---------------------------------------------------------------------------
__global__ __launch_bounds__(256)
void topk_k(const float* __restrict__ NEGc, int* __restrict__ IDX,
            int r0, int rows, int kd, int dil, int kout)
{
    __shared__ float vals[2500];
    __shared__ float wv_s[4];
    __shared__ int wi_s[4];
    int i = blockIdx.x;
    int b = blockIdx.y;
    const float* row = NEGc + ((size_t)b * rows + i) * 2500;
    int tid = threadIdx.x;
    int lane = tid & 63, wave = tid >> 6;
    // load row into LDS and build this thread's cached slice max
    float bv = -INFINITY;
    int bi = 0x7fffffff;
    for (int j = tid; j < 2500; j += 256) {
        float v = row[j];
        vals[j] = v;
        if (v > bv) { bv = v; bi = j; }
    }
    __syncthreads();
    for (int t = 0; t < kd; t++) {
        // wave-level shuffle reduce of (bv, bi), tie-break lower index
        float rv = bv; int ri = bi;
#pragma unroll
        for (int off = 32; off > 0; off >>= 1) {
            float ov = __shfl_xor(rv, off);
            int oi = __shfl_xor(ri, off);
            if (ov > rv || (ov == rv && oi < ri)) { rv = ov; ri = oi; }
        }
        if (lane == 0) { wv_s[wave] = rv; wi_s[wave] = ri; }
        __syncthreads();
        // all threads redundantly reduce the 4 wave partials
        float fv = wv_s[0]; int fi = wi_s[0];
#pragma unroll
        for (int w = 1; w < 4; w++) {
            float ov = wv_s[w]; int oi = wi_s[w];
            if (ov > fv || (ov == fv && oi < fi)) { fv = ov; fi = oi; }
        }
        int sel = fi;
        if ((unsigned)sel >= 2500u) sel = 0;   // fault-proof
        if (tid == 0 && t % dil == 0)
            IDX[(size_t)(b * 2500 + r0 + i) * kout + t / dil] = sel;
        __syncthreads();   // everyone done reading wv_s/wi_s before next round
        // owner invalidates and rebuilds its cached slice max
        if (tid == (sel & 0xff)) {
            vals[sel] = -INFINITY;
            bv = -INFINITY; bi = 0x7fffffff;
            for (int j = tid; j < 2500; j += 256) {
                float v = vals[j];
                if (v > bv) { bv = v; bi = j; }
            }
        }
    }
}

// ---------------------------------------------------------------------------
// Gather neighbors (round-7 code)
// ---------------------------------------------------------------------------
__global__ __launch_bounds__(256)
void gather_k(const float* __restrict__ HT, const int* __restrict__ IDX,
              float* __restrict__ F, int k)
{
    int t = blockIdx.x;
    int b = blockIdx.y;
    int q = threadIdx.x;
    __shared__ int idx[18];
    if (q < k) {
        int ii = IDX[((size_t)b * 2500 + t) * k + q];
        if ((unsigned)ii >= 2500u) ii = 0;
        idx[q] = ii;
    }
    __syncthreads();
    const float* base = HT + (size_t)b * 2500 * 256;
    float center = base[(size_t)t * 256 + q];
    float mx = -INFINITY;
    for (int kk = 0; kk < k; kk++) {
        float v = base[(size_t)idx[kk] * 256 + q];
        mx = fmaxf(mx, v - center);
    }
    float* Fp = F + (size_t)b * 512 * 2500;
    Fp[(size_t)(2 * q) * 2500 + t] = center;
    Fp[(size_t)(2 * q + 1) * 2500 + t] = mx;
}

__global__ __launch_bounds__(256)
void out_k(const float* __restrict__ X, float* __restrict__ out)
{
    int idx = blockIdx.x * 256 + threadIdx.x;
    if (idx >= 1280000) return;
    out[idx] = X[idx];
}

// ---------------------------------------------------------------------------
extern "C" void kernel_launch(void* const* d_in, const int* in_sizes, int n_in,
                              void* d_out, int out_size, void* d_ws, size_t ws_size,
                              hipStream_t stream)
{
    (void)in_sizes; (void)n_in; (void)out_size; (void)ws_size;
    const float* x_in = (const float*)d_in[0];
    const float *swp[5], *sbp[5], *sgp[5], *sbep[5];
    for (int i = 0; i < 5; i++) {
        swp[i] = (const float*)d_in[1 + 4 * i];
        sbp[i] = (const float*)d_in[2 + 4 * i];
        sgp[i] = (const float*)d_in[3 + 4 * i];
        sbep[i] = (const float*)d_in[4 + 4 * i];
    }
    const float* fc1_w = (const float*)d_in[21];
    const float* fc1_b = (const float*)d_in[22];
    const float* fc1_g = (const float*)d_in[23];
    const float* fc1_be = (const float*)d_in[24];
    const float* mr_w = (const float*)d_in[25];
    const float* mr_g = (const float*)d_in[26];
    const float* mr_be = (const float*)d_in[27];
    const float* fc2_w = (const float*)d_in[28];
    const float* fc2_b = (const float*)d_in[29];
    const float* fc2_g = (const float*)d_in[30];
    const float* fc2_be = (const float*)d_in[31];
    const float* ffn1_w = (const float*)d_in[32];
    const float* ffn1_b = (const float*)d_in[33];
    const float* ffn1_g = (const float*)d_in[34];
    const float* ffn1_be = (const float*)d_in[35];
    const float* ffn2_w = (const float*)d_in[36];
    const float* ffn2_b = (const float*)d_in[37];
    const float* ffn2_g = (const float*)d_in[38];
    const float* ffn2_be = (const float*)d_in[39];

    float* ws = (float*)d_ws;
    const size_t OA = 0, OB = 10240000, OC = 15360000, OD = 16640000;
    const size_t OSQ = 17920000, OR = 17925000, OPART = 17930000,
                 OFIN = 17932048, OIDX = 17932176;

    float* ping = ws + OA;
    float* pong = ws + OB;
    float* HF   = ws + OA;
    float* NEGc = ws + OA;
    float* F    = ws + OB;
    float* G    = ws + OB + 2560000;
    float* HF2  = ws + OB;
    float* X    = ws + OC;
    float* WT   = ws + OC;
    float* HT   = ws + OD;
    float* SQ   = ws + OSQ;
    float* R    = ws + OR;
    double* PART = (double*)(ws + OPART);
    float* FIN  = ws + OFIN;
    int* IDX = (int*)(ws + OIDX);

    // ---------------- stem ----------------
    int Co[5] = {32, 64, 128, 256, 256};
    int Ho[5] = {400, 200, 100, 50, 50};
    int Ssub[5] = {8, 8, 4, 2, 2};
    float* cur = nullptr;
    for (int l = 0; l < 5; l++) {
        float* outb = (l % 2 == 0) ? ping : pong;
        int HWo = Ho[l] * Ho[l];
        switch (l) {
        case 0:
            conv3x3_t<3, 16><<<dim3(625, 2, 2), 256, 0, stream>>>(
                x_in, swp[0], sbp[0], outb, 32, 800, 800, 400, 400, 2);
            break;
        case 1:
            conv3x3_t<32, 16><<<dim3(157, 4, 2), 256, 0, stream>>>(
                cur, swp[1], sbp[1], outb, 64, 400, 400, 200, 200, 2);
            break;
        case 2:
            conv3x3_t<64, 8><<<dim3(40, 16, 2), 256, 0, stream>>>(
                cur, swp[2], sbp[2], outb, 128, 200, 200, 100, 100, 2);
            break;
        case 3: {
            int tot = 9 * 128 * 256;
            wt_k<<<(tot + 255) / 256, 256, 0, stream>>>(swp[3], WT, 128, 256, tot);
            conv_gemm2_k<128><<<dim3(40, 8, 2), 256, 0, stream>>>(
                cur, WT, sbp[3], outb, 256, 100, 100, 50, 50, 2);
            break;
        }
        case 4: {
            int tot = 9 * 256 * 256;
            wt_k<<<(tot + 255) / 256, 256, 0, stream>>>(swp[4], WT, 256, 256, tot);
            conv_gemm2_k<256><<<dim3(40, 8, 2), 256, 0, stream>>>(
                cur, WT, sbp[4], outb, 256, 50, 50, 50, 50, 1);
            break;
        }
        }
        int cpg = Co[l] / 32;
        gn_stats_k<<<dim3(Ssub[l], 32, 2), 256, 0, stream>>>(outb, PART, Co[l], HWo, cpg, Ssub[l]);
        gn_reduce_k<<<1, 64, 0, stream>>>(PART, FIN, Ssub[l], (double)cpg * (double)HWo);
        int total = 2 * Co[l] * HWo;
        gn_apply_k<<<(total + 255) / 256, 256, 0, stream>>>(outb, FIN, sgp[l], sbep[l],
                                                            Co[l], HWo, cpg, (l < 4) ? 1 : 0, total);
        cur = outb;
    }
    posadd_k<<<(1280000 + 255) / 256, 256, 0, stream>>>(cur, X);

    // ---------------- 12 Grapher + FFN blocks ----------------
    const int KS[12] = {9, 9, 10, 11, 12, 13, 13, 14, 15, 16, 17, 18};
    const int DILS[12] = {1, 1, 1, 1, 2, 2, 2, 2, 3, 3, 3, 3};
    const int D = 256, N = 2500;
    const int CH = 2048;

    for (int i = 0; i < 12; i++) {
        gemm_k<<<dim3(40, 4, 2), 256, 0, stream>>>(
            fc1_w + (size_t)i * D * D, X, HF,
            fc1_b + i * D, fc1_g + i * D, fc1_be + i * D, nullptr, D, N, D, 0);
        tok_k<<<20, 256, 0, stream>>>(HF, HT, R, SQ);
        for (int r0 = 0; r0 < N; r0 += CH) {
            int rows = (N - r0 < CH) ? (N - r0) : CH;
            dist_k<<<dim3(40, (rows + 63) / 64, 2), 256, 0, stream>>>(HT, R, SQ, NEGc, r0, rows);
            topk_k<<<dim3(rows, 2), 256, 0, stream>>>(NEGc, IDX, r0, rows,
                                                      KS[i] * DILS[i], DILS[i], KS[i]);
        }
        gather_k<<<dim3(2500, 2), 256, 0, stream>>>(HT, IDX, F, KS[i]);
        gemm_k<<<dim3(40, 8, 2), 256, 0, stream>>>(
            mr_w + (size_t)i * 512 * 512, F, G,
            nullptr, mr_g + i * 512, mr_be + i * 512, nullptr, 512, N, 512, 1);
        gemm_k<<<dim3(40, 4, 2), 256, 0, stream>>>(
            fc2_w + (size_t)i * D * 512, G, X,
            fc2_b + i * D, fc2_g + i * D, fc2_be + i * D, X, D, N, 512, 0);
        gemm_k<<<dim3(40, 16, 2), 256, 0, stream>>>(
            ffn1_w + (size_t)i * 1024 * D, X, HF2,
            ffn1_b + i * 1024, ffn1_g + i * 1024, ffn1_be + i * 1024, nullptr, 1024, N, D, 1);
        gemm_k<<<dim3(40, 4, 2), 256, 0, stream>>>(
            ffn2_w + (size_t)i * D * 1024, HF2, X,
            ffn2_b + i * D, ffn2_g + i * D, ffn2_be + i * D, X, D, N, 1024, 0);
    }

    out_k<<<(1280000 + 255) / 256, 256, 0, stream>>>(X, (float*)d_out);
}

// Round 11
// 7480.174 us; speedup vs baseline: 1.1757x; 1.1757x over previous
//
#include <hip/hip_runtime.h>
#include <math.h>

#define DEVI static __device__ __forceinline__

DEVI float gelu_f(float x) { return 0.5f * x * (1.0f + erff(x * 0.70710678118654752440f)); }

// ---------------------------------------------------------------------------
// Direct 3x3 conv for small Cin (stem L0-L2), stage-all-taps. (round-7 code)
// ---------------------------------------------------------------------------
template <int CIN, int NCO>
__global__ __launch_bounds__(256)
void conv3x3_t(const float* __restrict__ in, const float* __restrict__ w,
               const float* __restrict__ bias, float* __restrict__ out,
               int Cout, int Hin, int Win, int Hout, int Wout, int stride)
{
    __shared__ __align__(16) float wlds[CIN * 9 * NCO];
    int b = blockIdx.z;
    int co0 = blockIdx.y * NCO;
    int tid = threadIdx.x;
    int HWo = Hout * Wout;
    int s = blockIdx.x * 256 + tid;
    int sc = (s < HWo) ? s : (HWo - 1);
    int ho = sc / Wout, wo = sc % Wout;
    float acc[NCO];
#pragma unroll
    for (int j = 0; j < NCO; j++) acc[j] = bias[co0 + j];
    const float* inb = in + (size_t)b * CIN * Hin * Win;
    size_t HWi = (size_t)Hin * Win;

    const int nw = NCO * CIN * 9;
    for (int i = tid; i < nw; i += 256) {
        int j = i % NCO;
        int rest = i / NCO;          // tap*CIN + ci
        int ci = rest % CIN, tap = rest / CIN;
        wlds[i] = w[((size_t)(co0 + j) * CIN + ci) * 9 + tap];
    }
    __syncthreads();
    for (int kh = 0; kh < 3; kh++) {
        int hi = ho * stride - 1 + kh;
        bool okh = (hi >= 0 && hi < Hin);
        for (int kw = 0; kw < 3; kw++) {
            int wi = wo * stride - 1 + kw;
            if (!okh || wi < 0 || wi >= Win) continue;
            int tap = kh * 3 + kw;
            const float* ip = inb + (size_t)hi * Win + wi;
            const float* wp = wlds + (size_t)tap * CIN * NCO;
#pragma unroll 8
            for (int ci = 0; ci < CIN; ci++) {
                float xv = ip[(size_t)ci * HWi];
                const float* wq = wp + ci * NCO;
#pragma unroll
                for (int j4 = 0; j4 < NCO; j4 += 4) {
                    float4 wv = *(const float4*)(wq + j4);
                    acc[j4 + 0] += xv * wv.x; acc[j4 + 1] += xv * wv.y;
                    acc[j4 + 2] += xv * wv.z; acc[j4 + 3] += xv * wv.w;
                }
            }
        }
    }
    if (s < HWo) {
        size_t ob = ((size_t)b * Cout + co0) * HWo + s;
#pragma unroll
        for (int j = 0; j < NCO; j++) out[ob + (size_t)j * HWo] = acc[j];
    }
}

// ---------------------------------------------------------------------------
// Weight transpose for conv L3/L4: w[co][ci][tap] -> WT[tap][ci][co]
// ---------------------------------------------------------------------------
__global__ __launch_bounds__(256)
void wt_k(const float* __restrict__ w, float* __restrict__ WT,
          int Cin, int Cout, int total)
{
    int idx = blockIdx.x * 256 + threadIdx.x;
    if (idx >= total) return;
    int co = idx % Cout;
    int rest = idx / Cout;
    int ci = rest % Cin;
    int tap = rest / Cin;
    WT[idx] = w[((size_t)co * Cin + ci) * 9 + tap];
}

// ---------------------------------------------------------------------------
// GEMM-style conv for large Cin (stem L3/L4), v2 (round-9 code, unchanged)
// ---------------------------------------------------------------------------
template <int CIN>
__global__ __launch_bounds__(256)
void conv_gemm2_k(const float* __restrict__ in, const float* __restrict__ WT,
                  const float* __restrict__ bias, float* __restrict__ out,
                  int Cout, int Hin, int Win, int Hout, int Wout, int stride)
{
    __shared__ __align__(16) float As[16][36];   // [k][co32]
    __shared__ __align__(16) float Bs[16][68];   // [k][site64]
    int b = blockIdx.z;
    int n0 = blockIdx.x * 64;                    // site tile
    int m0 = blockIdx.y * 32;                    // cout tile
    int HWo = Hout * Wout;
    int tid = threadIdx.x;
    int tx = tid % 16, ty = tid / 16;            // tx: 4 sites, ty: 2 couts
    int wa_c = tid % 32, wa_k = tid / 32;        // As staging: co fastest
    int lb_n = tid % 64, lb_k = tid / 64;        // Bs staging
    int sb = n0 + lb_n;
    int sbc = (sb < HWo) ? sb : (HWo - 1);
    int ho_b = sbc / Wout, wo_b = sbc % Wout;
    bool site_ok = (sb < HWo);
    const float* inb = in + (size_t)b * CIN * Hin * Win;
    size_t HWi = (size_t)Hin * Win;

    float acc[2][4];
#pragma unroll
    for (int i = 0; i < 2; i++) {
        float bs = bias[m0 + ty * 2 + i];
#pragma unroll
        for (int j = 0; j < 4; j++) acc[i][j] = bs;
    }

    for (int tap = 0; tap < 9; tap++) {
        int kh = tap / 3, kw = tap % 3;
        int hi = ho_b * stride - 1 + kh;
        int wi = wo_b * stride - 1 + kw;
        bool valid = site_ok && (hi >= 0) && (hi < Hin) && (wi >= 0) && (wi < Win);
        const float* ip = inb + (size_t)hi * Win + wi;
        const float* wt = WT + (size_t)tap * CIN * Cout;
        for (int k0 = 0; k0 < CIN; k0 += 16) {
#pragma unroll
            for (int r = 0; r < 2; r++) {
                int kk = wa_k + r * 8;
                As[kk][wa_c] = wt[(size_t)(k0 + kk) * Cout + m0 + wa_c];
            }
#pragma unroll
            for (int r = 0; r < 4; r++) {
                int kk = lb_k + r * 4;
                Bs[kk][lb_n] = valid ? ip[(size_t)(k0 + kk) * HWi] : 0.f;
            }
            __syncthreads();
#pragma unroll
            for (int kk = 0; kk < 16; kk++) {
                float2 av = *(const float2*)&As[kk][ty * 2];
                float4 bv = *(const float4*)&Bs[kk][tx * 4];
                acc[0][0] += av.x * bv.x; acc[0][1] += av.x * bv.y;
                acc[0][2] += av.x * bv.z; acc[0][3] += av.x * bv.w;
                acc[1][0] += av.y * bv.x; acc[1][1] += av.y * bv.y;
                acc[1][2] += av.y * bv.z; acc[1][3] += av.y * bv.w;
            }
            __syncthreads();
        }
    }
#pragma unroll
    for (int i = 0; i < 2; i++) {
        int m = m0 + ty * 2 + i;
#pragma unroll
        for (int j = 0; j < 4; j++) {
            int n = n0 + tx * 4 + j;
            if (n < HWo)
                out[((size_t)b * Cout + m) * HWo + n] = acc[i][j];
        }
    }
}

// ---------------------------------------------------------------------------
// GroupNorm, DETERMINISTIC (round-7 code)
// ---------------------------------------------------------------------------
__global__ __launch_bounds__(256)
void gn_stats_k(const float* __restrict__ x, double* __restrict__ part,
                int C, int HW, int cpg, int S)
{
    int srt = blockIdx.x, g = blockIdx.y, b = blockIdx.z;
    long len = (long)cpg * HW;
    long chunk = (len + S - 1) / S;
    long lo = (long)srt * chunk;
    long hi = lo + chunk; if (hi > len) hi = len;
    const float* xp = x + ((size_t)b * C + (size_t)g * cpg) * HW;
    double s1 = 0.0, s2 = 0.0;
    for (long i = lo + threadIdx.x; i < hi; i += 256) {
        double v = (double)xp[i];
        s1 += v; s2 += v * v;
    }
    __shared__ double r1[256], r2[256];
    r1[threadIdx.x] = s1; r2[threadIdx.x] = s2;
    __syncthreads();
    for (int t = 128; t > 0; t >>= 1) {
        if (threadIdx.x < t) { r1[threadIdx.x] += r1[threadIdx.x + t]; r2[threadIdx.x] += r2[threadIdx.x + t]; }
        __syncthreads();
    }
    if (threadIdx.x == 0) {
        size_t slot = ((size_t)(b * 32 + g) * S + srt) * 2;
        part[slot] = r1[0];
        part[slot + 1] = r2[0];
    }
}

__global__ __launch_bounds__(64)
void gn_reduce_k(const double* __restrict__ part, float* __restrict__ fin,
                 int S, double cnt)
{
    int t = threadIdx.x;
    double s1 = 0.0, s2 = 0.0;
    for (int s = 0; s < S; s++) {
        size_t slot = ((size_t)t * S + s) * 2;
        s1 += part[slot];
        s2 += part[slot + 1];
    }
    double m = s1 / cnt;
    double var = s2 / cnt - m * m;
    double inv = 1.0 / sqrt(var + 1e-5);
    fin[t * 2] = (float)m;
    fin[t * 2 + 1] = (float)inv;
}

__global__ __launch_bounds__(256)
void gn_apply_k(float* __restrict__ x, const float* __restrict__ fin,
                const float* __restrict__ gma, const float* __restrict__ bta,
                int C, int HW, int cpg, int do_gelu, int total)
{
    int idx = blockIdx.x * 256 + threadIdx.x;
    if (idx >= total) return;
    int c = (idx / HW) % C;
    int b = idx / (HW * C);
    int g = c / cpg;
    float m = fin[(b * 32 + g) * 2];
    float inv = fin[(b * 32 + g) * 2 + 1];
    float v = (x[idx] - m) * inv * gma[c] + bta[c];
    if (do_gelu) v = gelu_f(v);
    x[idx] = v;
}

// ---------------------------------------------------------------------------
// Add DETR sine position embedding (round-7 code)
// ---------------------------------------------------------------------------
__global__ __launch_bounds__(256)
void posadd_k(const float* __restrict__ xin, float* __restrict__ xout)
{
    int idx = blockIdx.x * 256 + threadIdx.x;
    if (idx >= 2 * 256 * 2500) return;
    int t = idx % 2500;
    int ch = (idx / 2500) % 256;
    int yy = t / 50, xx = t % 50;
    int cc = ch & 127;
    double v = (double)((ch < 128) ? (yy + 1) : (xx + 1));
    v = v * (6.283185307179586476925287 / 50.0);
    double e = (double)(2 * (cc >> 1)) / 128.0;
    double d = pow(10000.0, e);
    double a = v / d;
    double p = (cc & 1) ? cos(a) : sin(a);
    xout[idx] = xin[idx] + (float)p;
}

// ---------------------------------------------------------------------------
// Pointwise GEMM (round-7 code, byte-exact)
// ---------------------------------------------------------------------------
__global__ __launch_bounds__(256)
void gemm_k(const float* __restrict__ A, const float* __restrict__ Bm,
            float* __restrict__ Cm,
            const float* __restrict__ bias, const float* __restrict__ gma,
            const float* __restrict__ bta, const float* __restrict__ res,
            int M, int N, int K, int do_gelu)
{
    __shared__ __align__(16) float As[16][68];
    __shared__ __align__(16) float Bs[16][68];
    int b = blockIdx.z;
    const float* Bp = Bm + (size_t)b * K * N;
    float* Cp = Cm + (size_t)b * M * N;
    const float* Rp = res ? res + (size_t)b * M * N : nullptr;
    int n0 = blockIdx.x * 64, m0 = blockIdx.y * 64;
    int tid = threadIdx.x;
    int tx = tid % 16, ty = tid / 16;
    int la_k = tid % 16, la_m = tid / 16;
    int lb_n = tid % 64, lb_k = tid / 64;
    float acc[4][4] = {};
    for (int k0 = 0; k0 < K; k0 += 16) {
#pragma unroll
        for (int r = 0; r < 4; r++) {
            int m = la_m + r * 16;
            As[la_k][m] = A[(size_t)(m0 + m) * K + k0 + la_k];
        }
#pragma unroll
        for (int r = 0; r < 4; r++) {
            int kk = lb_k + r * 4;
            int n = n0 + lb_n;
            Bs[kk][lb_n] = (n < N) ? Bp[(size_t)(k0 + kk) * N + n] : 0.f;
        }
        __syncthreads();
#pragma unroll
        for (int kk = 0; kk < 16; kk++) {
            float4 av = *(const float4*)&As[kk][ty * 4];
            float4 bv = *(const float4*)&Bs[kk][tx * 4];
            acc[0][0] += av.x * bv.x; acc[0][1] += av.x * bv.y; acc[0][2] += av.x * bv.z; acc[0][3] += av.x * bv.w;
            acc[1][0] += av.y * bv.x; acc[1][1] += av.y * bv.y; acc[1][2] += av.y * bv.z; acc[1][3] += av.y * bv.w;
            acc[2][0] += av.z * bv.x; acc[2][1] += av.z * bv.y; acc[2][2] += av.z * bv.z; acc[2][3] += av.z * bv.w;
            acc[3][0] += av.w * bv.x; acc[3][1] += av.w * bv.y; acc[3][2] += av.w * bv.z; acc[3][3] += av.w * bv.w;
        }
        __syncthreads();
    }
#pragma unroll
    for (int i2 = 0; i2 < 4; i2++) {
        int m = m0 + ty * 4 + i2;
        float bs = bias ? bias[m] : 0.f;
        float gm = gma[m], bt = bta[m];
#pragma unroll
        for (int j2 = 0; j2 < 4; j2++) {
            int n = n0 + tx * 4 + j2;
            if (n < N) {
                float v = (acc[i2][j2] + bs) * gm + bt;
                if (do_gelu) v = gelu_f(v);
                if (Rp) v += Rp[(size_t)m * N + n];
                Cp[(size_t)m * N + n] = v;
            }
        }
    }
}

// ---------------------------------------------------------------------------
// Per-token transpose + norms (round-7 code)
// ---------------------------------------------------------------------------
__global__ __launch_bounds__(256)
void tok_k(const float* __restrict__ Hf, float* __restrict__ HT,
           float* __restrict__ R, float* __restrict__ SQ)
{
    int t = blockIdx.x * 256 + threadIdx.x;
    if (t >= 5000) return;
    int b = t / 2500, tt = t % 2500;
    const float* p = Hf + (size_t)b * 256 * 2500 + tt;
    float* ht = HT + (size_t)t * 256;
    double s = 0.0;
    for (int c = 0; c < 256; c++) {
        float v = p[(size_t)c * 2500];
        ht[c] = v;
        s += (double)v * v;
    }
    float r = (float)(1.0 / sqrt(s + 1e-12));
    double s2 = 0.0;
    for (int c = 0; c < 256; c++) {
        float xn = ht[c] * r;
        s2 += (double)xn * xn;
    }
    R[t] = r;
    SQ[t] = (float)s2;
}

// ---------------------------------------------------------------------------
// Pairwise neg sq distance (round-7 code, byte-exact 64x64 tile)
// ---------------------------------------------------------------------------
__global__ __launch_bounds__(256)
void dist_k(const float* __restrict__ HT, const float* __restrict__ R,
            const float* __restrict__ SQ, float* __restrict__ NEGc,
            int r0, int rows)
{
    __shared__ __align__(16) float As[16][68];
    __shared__ __align__(16) float Bs[16][68];
    int b = blockIdx.z;
    const float* Xp = HT + (size_t)b * 2500 * 256;
    const float* Rp = R + (size_t)b * 2500;
    const float* Sp = SQ + (size_t)b * 2500;
    float* Np = NEGc + (size_t)b * rows * 2500;
    int n0 = blockIdx.x * 64, m0 = blockIdx.y * 64;  // m0 chunk-local
    int tid = threadIdx.x;
    int tx = tid % 16, ty = tid / 16;
    int lk = tid % 16, lr = tid / 16;
    float acc[4][4] = {};
    for (int k0 = 0; k0 < 256; k0 += 16) {
#pragma unroll
        for (int r = 0; r < 4; r++) {
            int m = lr + r * 16;
            int gi = r0 + m0 + m;
            As[lk][m] = (gi < 2500) ? Xp[(size_t)gi * 256 + k0 + lk] * Rp[gi] : 0.f;
            int gj = n0 + m;
            Bs[lk][m] = (gj < 2500) ? Xp[(size_t)gj * 256 + k0 + lk] * Rp[gj] : 0.f;
        }
        __syncthreads();
#pragma unroll
        for (int kk = 0; kk < 16; kk++) {
            float4 av = *(const float4*)&As[kk][ty * 4];
            float4 bv = *(const float4*)&Bs[kk][tx * 4];
            acc[0][0] += av.x * bv.x; acc[0][1] += av.x * bv.y; acc[0][2] += av.x * bv.z; acc[0][3] += av.x * bv.w;
            acc[1][0] += av.y * bv.x; acc[1][1] += av.y * bv.y; acc[1][2] += av.y * bv.z; acc[1][3] += av.y * bv.w;
            acc[2][0] += av.z * bv.x; acc[2][1] += av.z * bv.y; acc[2][2] += av.z * bv.z; acc[2][3] += av.z * bv.w;
            acc[3][0] += av.w * bv.x; acc[3][1] += av.w * bv.y; acc[3][2] += av.w * bv.z; acc[3][3] += av.w * bv.w;
        }
        __syncthreads();
    }
#pragma unroll
    for (int i2 = 0; i2 < 4; i2++) {
        int ml = m0 + ty * 4 + i2;
        int gi = r0 + ml;
        if (ml >= rows || gi >= 2500) continue;
        float si = Sp[gi];
#pragma unroll
        for (int j2 = 0; j2 < 4; j2++) {
            int j = n0 + tx * 4 + j2;
            if (j >= 2500) continue;
            Np[(size_t)ml * 2500 + j] = 2.f * acc[i2][j2] - si - Sp[j];
        }
    }
}

// ---------------------------------------------------------------------------
// top-(k*dil) v3: ONE WAVE PER ROW, no __syncthreads. Packed 64-bit keys:
// key = (monotone(float) << 32) | (0xFFFFFFFF - idx)  ->  uint64 max ==
// (value desc, index asc) lexicographic winner == v1/v2 selection exactly.
// -0 canonicalized to +0 at load (+0.0f), preserving float-compare classes.
// Each lane owns contiguous 40-elem segment; cached segment-max key.
// Per round: 6-step 64b xor-shuffle reduce; owner invalidates vals[sel];
// whole wave rebuilds the owner's segment (1 LDS read/lane + reduce).
// ---------------------------------------------------------------------------
DEVI unsigned long long pack_key(float x, unsigned idx)
{
    unsigned u = __float_as_uint(x);
    u = (u & 0x80000000u) ? ~u : (u | 0x80000000u);
    return ((unsigned long long)u << 32) | (unsigned long long)(0xFFFFFFFFu - idx);
}

__global__ __launch_bounds__(128)
void topk_k(const float* __restrict__ NEGc, int* __restrict__ IDX,
            int rows, int kd, int dil, int kout)
{
    __shared__ float vals[2][2560];
    int wave = threadIdx.x >> 6;
    int lane = threadIdx.x & 63;
    int i = blockIdx.x * 2 + wave;       // row
    int b = blockIdx.z;
    if (i >= rows) return;               // whole wave exits; no barriers used
    const float* row = NEGc + ((size_t)b * rows + i) * 2500;
    float* v = vals[wave];
    for (int j = lane; j < 2560; j += 64)
        v[j] = (j < 2500) ? (row[j] + 0.0f) : -INFINITY;
    // build this lane's cached segment-max key (segment [lane*40, lane*40+40))
    unsigned long long key = pack_key(-INFINITY, 0xFFFFFFFFu);
    for (int q = 0; q < 40; q++) {
        int pos = lane * 40 + q;
        unsigned long long k2 = pack_key(v[pos], (unsigned)pos);
        if (k2 > key) key = k2;
    }
    for (int t = 0; t < kd; t++) {
        unsigned long long r = key;
#pragma unroll
        for (int off = 32; off > 0; off >>= 1) {
            unsigned long long o = __shfl_xor(r, off);
            if (o > r) r = o;
        }
        int sel = (int)(0xFFFFFFFFu - (unsigned)(r & 0xFFFFFFFFull));
        if ((unsigned)sel >= 2500u) sel = 0;   // fault-proof
        if (lane == 0 && t % dil == 0)
            IDX[(size_t)(b * 2500 + i) * kout + t / dil] = sel;
        int lo = sel / 40;
        if (lane == lo) v[sel] = -INFINITY;    // same-wave LDS: program order
        int pos = lo * 40 + lane;
        float x = (lane < 40) ? v[pos] : -INFINITY;
        unsigned long long k2 = pack_key(x, (lane < 40) ? (unsigned)pos : 0xFFFFFFFFu);
#pragma unroll
        for (int off = 32; off > 0; off >>= 1) {
            unsigned long long o = __shfl_xor(k2, off);
            if (o > k2) k2 = o;
        }
        if (lane == lo) key = k2;
    }
}

// ---------------------------------------------------------------------------
// Gather neighbors (round-7 code)
// ---------------------------------------------------------------------------
__global__ __launch_bounds__(256)
void gather_k(const float* __restrict__ HT, const int* __restrict__ IDX,
              float* __restrict__ F, int k)
{
    int t = blockIdx.x;
    int b = blockIdx.y;
    int q = threadIdx.x;
    __shared__ int idx[18];
    if (q < k) {
        int ii = IDX[((size_t)b * 2500 + t) * k + q];
        if ((unsigned)ii >= 2500u) ii = 0;
        idx[q] = ii;
    }
    __syncthreads();
    const float* base = HT + (size_t)b * 2500 * 256;
    float center = base[(size_t)t * 256 + q];
    float mx = -INFINITY;
    for (int kk = 0; kk < k; kk++) {
        float v = base[(size_t)idx[kk] * 256 + q];
        mx = fmaxf(mx, v - center);
    }
    float* Fp = F + (size_t)b * 512 * 2500;
    Fp[(size_t)(2 * q) * 2500 + t] = center;
    Fp[(size_t)(2 * q + 1) * 2500 + t] = mx;
}

__global__ __launch_bounds__(256)
void out_k(const float* __restrict__ X, float* __restrict__ out)
{
    int idx = blockIdx.x * 256 + threadIdx.x;
    if (idx >= 1280000) return;
    out[idx] = X[idx];
}

// ---------------------------------------------------------------------------
extern "C" void kernel_launch(void* const* d_in, const int* in_sizes, int n_in,
                              void* d_out, int out_size, void* d_ws, size_t ws_size,
                              hipStream_t stream)
{
    (void)in_sizes; (void)n_in; (void)out_size; (void)ws_size;
    const float* x_in = (const float*)d_in[0];
    const float *swp[5], *sbp[5], *sgp[5], *sbep[5];
    for (int i = 0; i < 5; i++) {
        swp[i] = (const float*)d_in[1 + 4 * i];
        sbp[i] = (const float*)d_in[2 + 4 * i];
        sgp[i] = (const float*)d_in[3 + 4 * i];
        sbep[i] = (const float*)d_in[4 + 4 * i];
    }
    const float* fc1_w = (const float*)d_in[21];
    const float* fc1_b = (const float*)d_in[22];
    const float* fc1_g = (const float*)d_in[23];
    const float* fc1_be = (const float*)d_in[24];
    const float* mr_w = (const float*)d_in[25];
    const float* mr_g = (const float*)d_in[26];
    const float* mr_be = (const float*)d_in[27];
    const float* fc2_w = (const float*)d_in[28];
    const float* fc2_b = (const float*)d_in[29];
    const float* fc2_g = (const float*)d_in[30];
    const float* fc2_be = (const float*)d_in[31];
    const float* ffn1_w = (const float*)d_in[32];
    const float* ffn1_b = (const float*)d_in[33];
    const float* ffn1_g = (const float*)d_in[34];
    const float* ffn1_be = (const float*)d_in[35];
    const float* ffn2_w = (const float*)d_in[36];
    const float* ffn2_b = (const float*)d_in[37];
    const float* ffn2_g = (const float*)d_in[38];
    const float* ffn2_be = (const float*)d_in[39];

    float* ws = (float*)d_ws;
    // ---- workspace (fp32), ~72.1 MiB, lifetime-aliased ----
    // kNN phase: NEGc spans A+B ([2][2500][2500] = 12.5M < 15.36M); F/G/HF2
    // (region B) are dead during dist+topk; gather writes F only afterwards.
    const size_t OA = 0, OB = 10240000, OC = 15360000, OD = 16640000;
    const size_t OSQ = 17920000, OR = 17925000, OPART = 17930000,
                 OFIN = 17932048, OIDX = 17932176;

    float* ping = ws + OA;
    float* pong = ws + OB;
    float* HF   = ws + OA;
    float* NEGc = ws + OA;              // 12.5M floats during kNN (A+B)
    float* F    = ws + OB;
    float* G    = ws + OB + 2560000;
    float* HF2  = ws + OB;
    float* X    = ws + OC;
    float* WT   = ws + OC;
    float* HT   = ws + OD;
    float* SQ   = ws + OSQ;
    float* R    = ws + OR;
    double* PART = (double*)(ws + OPART);
    float* FIN  = ws + OFIN;
    int* IDX = (int*)(ws + OIDX);

    // ---------------- stem ----------------
    int Co[5] = {32, 64, 128, 256, 256};
    int Ho[5] = {400, 200, 100, 50, 50};
    int Ssub[5] = {8, 8, 4, 2, 2};
    float* cur = nullptr;
    for (int l = 0; l < 5; l++) {
        float* outb = (l % 2 == 0) ? ping : pong;
        int HWo = Ho[l] * Ho[l];
        switch (l) {
        case 0:
            conv3x3_t<3, 16><<<dim3(625, 2, 2), 256, 0, stream>>>(
                x_in, swp[0], sbp[0], outb, 32, 800, 800, 400, 400, 2);
            break;
        case 1:
            conv3x3_t<32, 16><<<dim3(157, 4, 2), 256, 0, stream>>>(
                cur, swp[1], sbp[1], outb, 64, 400, 400, 200, 200, 2);
            break;
        case 2:
            conv3x3_t<64, 8><<<dim3(40, 16, 2), 256, 0, stream>>>(
                cur, swp[2], sbp[2], outb, 128, 200, 200, 100, 100, 2);
            break;
        case 3: {
            int tot = 9 * 128 * 256;
            wt_k<<<(tot + 255) / 256, 256, 0, stream>>>(swp[3], WT, 128, 256, tot);
            conv_gemm2_k<128><<<dim3(40, 8, 2), 256, 0, stream>>>(
                cur, WT, sbp[3], outb, 256, 100, 100, 50, 50, 2);
            break;
        }
        case 4: {
            int tot = 9 * 256 * 256;
            wt_k<<<(tot + 255) / 256, 256, 0, stream>>>(swp[4], WT, 256, 256, tot);
            conv_gemm2_k<256><<<dim3(40, 8, 2), 256, 0, stream>>>(
                cur, WT, sbp[4], outb, 256, 50, 50, 50, 50, 1);
            break;
        }
        }
        int cpg = Co[l] / 32;
        gn_stats_k<<<dim3(Ssub[l], 32, 2), 256, 0, stream>>>(outb, PART, Co[l], HWo, cpg, Ssub[l]);
        gn_reduce_k<<<1, 64, 0, stream>>>(PART, FIN, Ssub[l], (double)cpg * (double)HWo);
        int total = 2 * Co[l] * HWo;
        gn_apply_k<<<(total + 255) / 256, 256, 0, stream>>>(outb, FIN, sgp[l], sbep[l],
                                                            Co[l], HWo, cpg, (l < 4) ? 1 : 0, total);
        cur = outb;
    }
    posadd_k<<<(1280000 + 255) / 256, 256, 0, stream>>>(cur, X);

    // ---------------- 12 Grapher + FFN blocks ----------------
    const int KS[12] = {9, 9, 10, 11, 12, 13, 13, 14, 15, 16, 17, 18};
    const int DILS[12] = {1, 1, 1, 1, 2, 2, 2, 2, 3, 3, 3, 3};
    const int D = 256, N = 2500;

    for (int i = 0; i < 12; i++) {
        gemm_k<<<dim3(40, 4, 2), 256, 0, stream>>>(
            fc1_w + (size_t)i * D * D, X, HF,
            fc1_b + i * D, fc1_g + i * D, fc1_be + i * D, nullptr, D, N, D, 0);
        tok_k<<<20, 256, 0, stream>>>(HF, HT, R, SQ);
        // full pairwise distances (NEGc spans A+B) + wave-per-row top-k
        dist_k<<<dim3(40, 40, 2), 256, 0, stream>>>(HT, R, SQ, NEGc, 0, N);
        topk_k<<<dim3(1250, 1, 2), 128, 0, stream>>>(NEGc, IDX, N,
                                                     KS[i] * DILS[i], DILS[i], KS[i]);
        gather_k<<<dim3(2500, 2), 256, 0, stream>>>(HT, IDX, F, KS[i]);
        gemm_k<<<dim3(40, 8, 2), 256, 0, stream>>>(
            mr_w + (size_t)i * 512 * 512, F, G,
            nullptr, mr_g + i * 512, mr_be + i * 512, nullptr, 512, N, 512, 1);
        gemm_k<<<dim3(40, 4, 2), 256, 0, stream>>>(
            fc2_w + (size_t)i * D * 512, G, X,
            fc2_b + i * D, fc2_g + i * D, fc2_be + i * D, X, D, N, 512, 0);
        gemm_k<<<dim3(40, 16, 2), 256, 0, stream>>>(
            ffn1_w + (size_t)i * 1024 * D, X, HF2,
            ffn1_b + i * 1024, ffn1_g + i * 1024, ffn1_be + i * 1024, nullptr, 1024, N, D, 1);
        gemm_k<<<dim3(40, 4, 2), 256, 0, stream>>>(
            ffn2_w + (size_t)i * D * 1024, HF2, X,
            ffn2_b + i * D, ffn2_g + i * D, ffn2_be + i * D, X, D, N, 1024, 0);
    }

    out_k<<<(1280000 + 255) / 256, 256, 0, stream>>>(X, (float*)d_out);
}